// Round 3
// baseline (465.071 us; speedup 1.0000x reference)
//
#include <hip/hip_runtime.h>
#include <math.h>

#define BATCH 8192
#define HDIM  1024
#define KDIM  2048

typedef __attribute__((ext_vector_type(8))) short short8;
typedef __attribute__((ext_vector_type(4))) float floatx4;

__device__ __forceinline__ float b2f(unsigned short u) {
  union { unsigned int i; float f; } v; v.i = ((unsigned int)u) << 16; return v.f;
}
__device__ __forceinline__ unsigned short f2b(float f) {
  union { unsigned int i; float f; } v; v.f = f;
  unsigned int r = v.i + 0x7FFFu + ((v.i >> 16) & 1u);
  return (unsigned short)(r >> 16);
}
__device__ __forceinline__ float ldsel(const void* p, size_t i, int isbf) {
  return isbf ? b2f(((const unsigned short*)p)[i]) : ((const float*)p)[i];
}
__device__ __forceinline__ void stsel(void* p, size_t i, int isbf, float v) {
  if (isbf) ((unsigned short*)p)[i] = f2b(v);
  else ((float*)p)[i] = v;
}
__device__ __forceinline__ float sigf(float x) { return 1.0f / (1.0f + __expf(-x)); }
__device__ __forceinline__ float tanhfast(float x) {
  float a = __builtin_fabsf(x);
  float t = __expf(-2.f * a);
  float r = (1.f - t) / (1.f + t);
  return copysignf(r, x);
}

// wave-uniform dtype detect from x[0..63]; identical result in every wave.
__device__ __forceinline__ int detect_bf(const void* x) {
  unsigned int w = ((const unsigned int*)x)[threadIdx.x & 63];
  unsigned short lo = (unsigned short)(w & 0xFFFFu);
  int e = (lo >> 7) & 0xFF;
  bool ok = (e >= 110 && e <= 135) || ((lo & 0x7FFFu) == 0);
  unsigned long long m = __ballot(ok);
  return (__popcll(m) >= 48) ? 1 : 0;
}

// async 16B global->LDS
__device__ __forceinline__ void gld16(const void* g, void* l) {
  auto gp = reinterpret_cast<__attribute__((address_space(1))) unsigned int*>(
      (unsigned long long)g);
  auto lp = reinterpret_cast<__attribute__((address_space(3))) unsigned int*>(
      (unsigned long long)l);
  __builtin_amdgcn_global_load_lds(gp, lp, 16, 0, 0);
}

// ------------------------------------------------------------------ pack (all)
// blocks [0,1536): WT pack; block 1536: W1T pack; blocks >1536: f32 A-pack.
__global__ __launch_bounds__(256) void k_pack(
    const void* __restrict__ x, const void* __restrict__ h,
    const void* __restrict__ wxi, const void* __restrict__ whi,
    const void* __restrict__ wxc, const void* __restrict__ whc,
    const void* __restrict__ wxo, const void* __restrict__ who,
    const void* __restrict__ W1,
    unsigned short* __restrict__ WT, unsigned short* __restrict__ W1T,
    unsigned short* __restrict__ A) {
  const int isbf = detect_bf(x);
  const int bx = blockIdx.x;
  const int t = threadIdx.x;
  if (bx < 1536) {
    const int mat = bx >> 8;
    const int rem = bx & 255;
    const int ti = rem >> 4;      // k-tile
    const int tj = rem & 15;      // hid-tile
    const void* Ws[6] = {wxi, whi, wxc, whc, wxo, who};
    const void* W = Ws[mat];
    const int gt = mat >> 1;
    const int half = mat & 1;
    __shared__ float tbuf[64][65];
    const int rrow = t >> 3;
    const int c8 = (t & 7) * 8;
#pragma unroll
    for (int it = 0; it < 2; ++it) {
      int row = it * 32 + rrow;
      size_t off = (size_t)(ti * 64 + row) * 1024 + tj * 64 + c8;
      if (isbf) {
        const unsigned short* s = (const unsigned short*)W + off;
        ushort4 a = *(const ushort4*)(s);
        ushort4 b = *(const ushort4*)(s + 4);
        tbuf[row][c8+0]=b2f(a.x); tbuf[row][c8+1]=b2f(a.y);
        tbuf[row][c8+2]=b2f(a.z); tbuf[row][c8+3]=b2f(a.w);
        tbuf[row][c8+4]=b2f(b.x); tbuf[row][c8+5]=b2f(b.y);
        tbuf[row][c8+6]=b2f(b.z); tbuf[row][c8+7]=b2f(b.w);
      } else {
        const float* s = (const float*)W + off;
        float4 a = *(const float4*)(s);
        float4 b = *(const float4*)(s + 4);
        tbuf[row][c8+0]=a.x; tbuf[row][c8+1]=a.y; tbuf[row][c8+2]=a.z; tbuf[row][c8+3]=a.w;
        tbuf[row][c8+4]=b.x; tbuf[row][c8+5]=b.y; tbuf[row][c8+6]=b.z; tbuf[row][c8+7]=b.w;
      }
    }
    __syncthreads();
#pragma unroll
    for (int it = 0; it < 2; ++it) {
      int nl = it * 32 + rrow;
      int n = gt * 1024 + tj * 64 + nl;
      int kb = half * 1024 + ti * 64 + c8;
      short8 pk;
#pragma unroll
      for (int i = 0; i < 8; ++i) pk[i] = (short)f2b(tbuf[c8 + i][nl]);
      *(short8*)(WT + (size_t)n * KDIM + kb) = pk;
    }
  } else if (bx == 1536) {
    for (int k = t; k < 2048; k += 256) {
      unsigned short v[16];
      if (isbf) {
        const unsigned short* r = (const unsigned short*)W1 + (size_t)k * 16;
#pragma unroll
        for (int i = 0; i < 16; ++i) v[i] = r[i];
      } else {
        const float* r = (const float*)W1 + (size_t)k * 16;
#pragma unroll
        for (int i = 0; i < 16; ++i) v[i] = f2b(r[i]);
      }
#pragma unroll
      for (int nn = 0; nn < 16; ++nn) W1T[(size_t)nn * 2048 + k] = v[nn];
    }
  } else {
    if (isbf) return;  // bf16: gemm/z2 read x,h directly
    size_t idx = ((size_t)(bx - 1537) * 256 + t) * 8;
    int k = (int)(idx & 2047);
    size_t m = idx >> 11;
    const float* s = (k < 1024) ? (const float*)x + m * 1024 + k
                                : (const float*)h + m * 1024 + (k - 1024);
    float4 a = *(const float4*)(s);
    float4 b = *(const float4*)(s + 4);
    short8 pk;
    pk[0]=(short)f2b(a.x); pk[1]=(short)f2b(a.y); pk[2]=(short)f2b(a.z); pk[3]=(short)f2b(a.w);
    pk[4]=(short)f2b(b.x); pk[5]=(short)f2b(b.y); pk[6]=(short)f2b(b.z); pk[7]=(short)f2b(b.w);
    *(short8*)(A + idx) = pk;
  }
}

// ---------------------------------------------------------------- z2 (MLP 1+2)
// 256 threads, 4 waves split-K over 16 batch rows; LDS reduce; z2 f32 [8192][8].
__global__ __launch_bounds__(256) void k_z2(
    const void* __restrict__ x, const void* __restrict__ h,
    const unsigned short* __restrict__ Apack,
    const unsigned short* __restrict__ W1T,
    const void* __restrict__ b1, const void* __restrict__ W2,
    const void* __restrict__ b2, float* __restrict__ z2) {
  const int isbf = detect_bf(x);
  const unsigned short* Ax = isbf ? (const unsigned short*)x : Apack;
  const unsigned short* Ah = isbf ? (const unsigned short*)h : (Apack + 1024);
  const int sA = isbf ? 1024 : 2048;
  const int tid = threadIdx.x;
  const int w = tid >> 6;
  const int lane = tid & 63;
  const int q = lane >> 4;
  const int r = lane & 15;
  const int m0 = blockIdx.x * 16;
  const unsigned short* ar =
      ((w >> 1) ? Ah : Ax) + (size_t)(m0 + r) * sA + (w & 1) * 512;
  const unsigned short* br = W1T + (size_t)r * 2048 + (w >> 1) * 1024 + (w & 1) * 512;
  floatx4 acc = {0.f, 0.f, 0.f, 0.f};
#pragma unroll 4
  for (int kt = 0; kt < 16; ++kt) {
    int k = kt * 32 + q * 8;
    short8 a = *(const short8*)(ar + k);
    short8 b = *(const short8*)(br + k);
    acc = __builtin_amdgcn_mfma_f32_16x16x32_bf16(a, b, acc, 0, 0, 0);
  }
  __shared__ float part[4][16][17];
  __shared__ float z1s[16][17];
#pragma unroll
  for (int t = 0; t < 4; ++t) part[w][q * 4 + t][r] = acc[t];
  __syncthreads();
  {
    const int row = tid >> 4;
    const int n = tid & 15;
    float s = part[0][row][n] + part[1][row][n] + part[2][row][n] +
              part[3][row][n] + ldsel(b1, (size_t)n, isbf);
    z1s[row][n] = fmaxf(s, 0.f);
  }
  __syncthreads();
  if (tid < 128) {
    const int row = tid >> 3;
    const int p = tid & 7;
    float s = ldsel(b2, (size_t)p, isbf);
#pragma unroll
    for (int nn = 0; nn < 16; ++nn)
      s += z1s[row][nn] * ldsel(W2, (size_t)nn * 8 + p, isbf);
    z2[(size_t)(m0 + row) * 8 + p] = fmaxf(s, 0.f);
  }
}

// ------------------------------------------------------- fused GEMM + LSTM
// Block: 128 m x 64 hid x 3 gates. acc[3][4][2]. LDS: A 16KB + B 3x8KB = 40KB.
// Epilogue computes f (z2@W3), c_new, h_new, writes all outputs. No P buffer.
__global__ __launch_bounds__(256, 3) void k_gemm_fused(
    const void* __restrict__ x, const void* __restrict__ h,
    const unsigned short* __restrict__ Apack,
    const unsigned short* __restrict__ WT,
    const void* __restrict__ cin,
    const void* __restrict__ bi, const void* __restrict__ bc,
    const void* __restrict__ bo,
    const float* __restrict__ z2,
    const void* __restrict__ W3, const void* __restrict__ b3,
    void* __restrict__ out) {
  const int isbf = detect_bf(x);
  const unsigned short* Ax = isbf ? (const unsigned short*)x : Apack;
  const unsigned short* Ah = isbf ? (const unsigned short*)h : (Apack + 1024);
  const int sA = isbf ? 1024 : 2048;
  __shared__ __align__(16) unsigned short lA[128 * 64];
  __shared__ __align__(16) unsigned short lB[3 * 64 * 64];
  const int tid = threadIdx.x;
  const int lane = tid & 63;
  const int wv = tid >> 6;
  const int wm = (wv >> 1) << 6;   // 0 / 64
  const int wn = (wv & 1) << 5;    // 0 / 32
  const int m0 = (blockIdx.x & 63) << 7;
  const int n0h = (blockIdx.x >> 6) << 6;   // hid base, 0..960

  floatx4 acc[3][4][2];
  const floatx4 fzero = {0.f, 0.f, 0.f, 0.f};
#pragma unroll
  for (int g = 0; g < 3; ++g)
#pragma unroll
    for (int i = 0; i < 4; ++i)
#pragma unroll
      for (int j = 0; j < 2; ++j) acc[g][i][j] = fzero;

  const int px0 = (lane >> 4) ^ (lane & 7);
  const int px1 = ((lane >> 4) + 4) ^ (lane & 7);
  const int rowA = wm + (lane & 15);
  const int rowB = wn + (lane & 15);

  for (int kt = 0; kt < KDIM / 64; ++kt) {
    const int k0 = kt * 64;
    const unsigned short* Abase = (k0 < 1024) ? (Ax + k0) : (Ah + (k0 - 1024));
#pragma unroll
    for (int ps = 0; ps < 4; ++ps) {
      const int chunk = ps * 256 + tid;
      const int row = chunk >> 3;
      const int kc = (chunk & 7) ^ (row & 7);
      gld16(Abase + (size_t)(m0 + row) * sA + kc * 8, lA + chunk * 8);
    }
#pragma unroll
    for (int ps = 0; ps < 6; ++ps) {
      const int chunk = ps * 256 + tid;
      const int g = chunk >> 9;
      const int row = (chunk >> 3) & 63;
      const int kc = (chunk & 7) ^ (row & 7);
      gld16(WT + ((size_t)(g * 1024 + n0h + row) * KDIM + k0 + kc * 8),
            lB + chunk * 8);
    }
    __syncthreads();
#pragma unroll
    for (int s = 0; s < 2; ++s) {
      const int px = s ? px1 : px0;
      short8 af[4];
#pragma unroll
      for (int i = 0; i < 4; ++i)
        af[i] = *(const short8*)(lA + ((((rowA + (i << 4)) << 3) + px) << 3));
#pragma unroll
      for (int g = 0; g < 3; ++g) {
        short8 b0 = *(const short8*)(lB + ((((g * 64 + rowB) << 3) + px) << 3));
        short8 b1 = *(const short8*)(lB + ((((g * 64 + rowB + 16) << 3) + px) << 3));
#pragma unroll
        for (int mi = 0; mi < 4; ++mi) {
          acc[g][mi][0] = __builtin_amdgcn_mfma_f32_16x16x32_bf16(
              af[mi], b0, acc[g][mi][0], 0, 0, 0);
          acc[g][mi][1] = __builtin_amdgcn_mfma_f32_16x16x32_bf16(
              af[mi], b1, acc[g][mi][1], 0, 0, 0);
        }
      }
    }
    __syncthreads();
  }

  // epilogue: C/D layout col=lane&15 (hid), row=(lane>>4)*4+t (m)
  const size_t MH = (size_t)BATCH * HDIM;
  const int col = lane & 15;
  const int rbase = (lane >> 4) << 2;
#pragma unroll
  for (int mi = 0; mi < 4; ++mi) {
#pragma unroll
    for (int ni = 0; ni < 2; ++ni) {
      const int n = n0h + wn + (ni << 4) + col;   // hid index
      float w3v[8];
#pragma unroll
      for (int j = 0; j < 8; ++j) w3v[j] = ldsel(W3, (size_t)j * 1024 + n, isbf);
      const float b3v = ldsel(b3, (size_t)n, isbf);
      const float biv = ldsel(bi, (size_t)n, isbf);
      const float bcv = ldsel(bc, (size_t)n, isbf);
      const float bov = ldsel(bo, (size_t)n, isbf);
#pragma unroll
      for (int t = 0; t < 4; ++t) {
        const size_t m = (size_t)(m0 + wm + (mi << 4) + rbase + t);
        const float* zr = z2 + m * 8;
        float f3 = b3v;
#pragma unroll
        for (int j = 0; j < 8; ++j) f3 += zr[j] * w3v[j];
        const float F = sigf(f3);
        const float I = sigf(acc[0][mi][ni][t] + biv);
        const float G = tanhfast(acc[1][mi][ni][t] + bcv);
        const float O = sigf(acc[2][mi][ni][t] + bov);
        const float cv = ldsel(cin, m * 1024 + n, isbf);
        const float C = F * cv + I * G;
        const float H = O * tanhfast(C);
        stsel(out, m * 1024 + n, isbf, H);
        stsel(out, MH + m * 1024 + n, isbf, C);
        stsel(out, 2 * MH + m * 1024 + n, isbf, F);
      }
    }
  }
}

extern "C" void kernel_launch(void* const* d_in, const int* in_sizes, int n_in,
                              void* d_out, int out_size, void* d_ws, size_t ws_size,
                              hipStream_t stream) {
  const void* x    = d_in[0];
  const void* h    = d_in[1];
  const void* c    = d_in[2];
  const void* W_hi = d_in[3];
  const void* W_xi = d_in[4];
  const void* b_i  = d_in[5];
  const void* W_hc = d_in[6];
  const void* W_xc = d_in[7];
  const void* b_c  = d_in[8];
  const void* W_ho = d_in[9];
  const void* W_xo = d_in[10];
  const void* b_o  = d_in[11];
  const void* W1   = d_in[12];
  const void* b1   = d_in[13];
  const void* W2   = d_in[14];
  const void* b2   = d_in[15];
  const void* W3   = d_in[16];
  const void* b3   = d_in[17];

  char* ws = (char*)d_ws;
  unsigned short* A   = (unsigned short*)ws;                 // 33.5 MB (f32 path)
  unsigned short* WT  = (unsigned short*)(ws + 33554432);    // 12.6 MB
  float*          z2b = (float*)(ws + 46137344);             // 256 KB
  unsigned short* W1T = (unsigned short*)(ws + 46399488);    // 64 KB

  k_pack<<<dim3(1537 + 8192), dim3(256), 0, stream>>>(
      x, h, W_xi, W_hi, W_xc, W_hc, W_xo, W_ho, W1, WT, W1T, A);
  k_z2<<<dim3(BATCH / 16), dim3(256), 0, stream>>>(x, h, A, W1T, b1, W2, b2, z2b);
  k_gemm_fused<<<dim3(64 * 16), dim3(256), 0, stream>>>(
      x, h, A, WT, c, b_i, b_c, b_o, z2b, W3, b3, d_out);
}

// Round 4
// 374.230 us; speedup vs baseline: 1.2427x; 1.2427x over previous
//
#include <hip/hip_runtime.h>
#include <math.h>

#define BATCH 8192
#define HDIM  1024
#define KDIM  2048
#define NDIM  3072

typedef __attribute__((ext_vector_type(8))) short short8;
typedef __attribute__((ext_vector_type(4))) float floatx4;

__device__ __forceinline__ float b2f(unsigned short u) {
  union { unsigned int i; float f; } v; v.i = ((unsigned int)u) << 16; return v.f;
}
__device__ __forceinline__ unsigned short f2b(float f) {
  union { unsigned int i; float f; } v; v.f = f;
  unsigned int r = v.i + 0x7FFFu + ((v.i >> 16) & 1u);
  return (unsigned short)(r >> 16);
}
__device__ __forceinline__ float ldsel(const void* p, size_t i, int isbf) {
  return isbf ? b2f(((const unsigned short*)p)[i]) : ((const float*)p)[i];
}
__device__ __forceinline__ float sigf(float x) { return 1.0f / (1.0f + __expf(-x)); }
__device__ __forceinline__ float tanhfast(float x) {
  float a = __builtin_fabsf(x);
  float t = __expf(-2.f * a);
  float r = (1.f - t) / (1.f + t);
  return copysignf(r, x);
}

// wave-uniform dtype detect from x[0..63]
__device__ __forceinline__ int detect_bf(const void* x) {
  unsigned int w = ((const unsigned int*)x)[threadIdx.x & 63];
  unsigned short lo = (unsigned short)(w & 0xFFFFu);
  int e = (lo >> 7) & 0xFF;
  bool ok = (e >= 110 && e <= 135) || ((lo & 0x7FFFu) == 0);
  unsigned long long m = __ballot(ok);
  return (__popcll(m) >= 48) ? 1 : 0;
}

// async 16B global->LDS
__device__ __forceinline__ void gld16(const void* g, void* l) {
  auto gp = reinterpret_cast<__attribute__((address_space(1))) unsigned int*>(
      (unsigned long long)g);
  auto lp = reinterpret_cast<__attribute__((address_space(3))) unsigned int*>(
      (unsigned long long)l);
  __builtin_amdgcn_global_load_lds(gp, lp, 16, 0, 0);
}

// load 8 bf16 (as short8) from either-format source at element offset
__device__ __forceinline__ short8 ld8bf(const void* p, size_t off, int isbf) {
  short8 r;
  if (isbf) {
    r = *(const short8*)((const unsigned short*)p + off);
  } else {
    const float* s = (const float*)p + off;
    float4 a = *(const float4*)(s);
    float4 b = *(const float4*)(s + 4);
    r[0]=(short)f2b(a.x); r[1]=(short)f2b(a.y); r[2]=(short)f2b(a.z); r[3]=(short)f2b(a.w);
    r[4]=(short)f2b(b.x); r[5]=(short)f2b(b.y); r[6]=(short)f2b(b.z); r[7]=(short)f2b(b.w);
  }
  return r;
}

// =============================================================== k_all
// blocks [0,512): z2 MLP; [512,2048): WT pack; [2048,10240): f32 A-pack.
__global__ __launch_bounds__(256) void k_all(
    const void* __restrict__ x, const void* __restrict__ h,
    const void* __restrict__ wxi, const void* __restrict__ whi,
    const void* __restrict__ wxc, const void* __restrict__ whc,
    const void* __restrict__ wxo, const void* __restrict__ who,
    const void* __restrict__ W1, const void* __restrict__ b1,
    const void* __restrict__ W2, const void* __restrict__ b2,
    unsigned short* __restrict__ WT, unsigned short* __restrict__ A,
    float* __restrict__ z2) {
  __shared__ __align__(16) char smem[70976];
  const int isbf = detect_bf(x);
  const int bx = blockIdx.x;
  const int tid = threadIdx.x;

  if (bx < 512) {
    // ---------------- z2 blocks: 16 batch rows each, split-K over 4 waves
    unsigned short* lW = (unsigned short*)smem;          // [16][2048] swizzled
    float* part = (float*)(smem + 65536);                // [4][16][17]
    float* z1s  = (float*)(smem + 69888);                // [16][17]
    const int m0 = bx * 16;
    // stage W1 transposed into LDS: lW(row,k) at row*2048 + ((k>>3)^(row&7))*8 + (k&7)
#pragma unroll
    for (int it = 0; it < 16; ++it) {
      const int chunk = it * 256 + tid;   // 4096 chunks
      const int k = chunk >> 1;
      const int jh = (chunk & 1) * 8;
      unsigned short v[8];
      if (isbf) {
        short8 s = *(const short8*)((const unsigned short*)W1 + (size_t)k * 16 + jh);
#pragma unroll
        for (int j = 0; j < 8; ++j) v[j] = (unsigned short)s[j];
      } else {
        const float* s = (const float*)W1 + (size_t)k * 16 + jh;
        float4 a = *(const float4*)(s);
        float4 b = *(const float4*)(s + 4);
        v[0]=f2b(a.x); v[1]=f2b(a.y); v[2]=f2b(a.z); v[3]=f2b(a.w);
        v[4]=f2b(b.x); v[5]=f2b(b.y); v[6]=f2b(b.z); v[7]=f2b(b.w);
      }
#pragma unroll
      for (int j = 0; j < 8; ++j) {
        const int row = jh + j;
        lW[row * 2048 + (((k >> 3) ^ (row & 7)) << 3) + (k & 7)] = v[j];
      }
    }
    __syncthreads();
    const int w = tid >> 6;
    const int lane = tid & 63;
    const int q = lane >> 4;
    const int r = lane & 15;
    const void* src = (w >> 1) ? h : x;
    const size_t abase = (size_t)(m0 + r) * 1024 + (w & 1) * 512;
    const int kb = (w >> 1) * 1024 + (w & 1) * 512;   // global k base for B
    floatx4 acc = {0.f, 0.f, 0.f, 0.f};
#pragma unroll 4
    for (int kt = 0; kt < 16; ++kt) {
      const int kl = kt * 32 + q * 8;
      short8 a = ld8bf(src, abase + kl, isbf);
      const int kg = kb + kl;
      short8 b = *(const short8*)(lW + r * 2048 + (((kg >> 3) ^ (r & 7)) << 3));
      acc = __builtin_amdgcn_mfma_f32_16x16x32_bf16(a, b, acc, 0, 0, 0);
    }
#pragma unroll
    for (int t = 0; t < 4; ++t) part[(w * 16 + q * 4 + t) * 17 + r] = acc[t];
    __syncthreads();
    {
      const int row = tid >> 4;
      const int n = tid & 15;
      float s = part[(0 * 16 + row) * 17 + n] + part[(1 * 16 + row) * 17 + n] +
                part[(2 * 16 + row) * 17 + n] + part[(3 * 16 + row) * 17 + n] +
                ldsel(b1, (size_t)n, isbf);
      z1s[row * 17 + n] = fmaxf(s, 0.f);
    }
    __syncthreads();
    if (tid < 128) {
      const int row = tid >> 3;
      const int p = tid & 7;
      float s = ldsel(b2, (size_t)p, isbf);
#pragma unroll
      for (int nn = 0; nn < 16; ++nn)
        s += z1s[row * 17 + nn] * ldsel(W2, (size_t)nn * 8 + p, isbf);
      z2[(size_t)(m0 + row) * 8 + p] = fmaxf(s, 0.f);
    }
  } else if (bx < 2048) {
    // ---------------- WT pack: WT[n][k], n = gate*1024+hid
    float (*tbuf)[65] = (float(*)[65])smem;
    const int b = bx - 512;
    const int mat = b >> 8;
    const int rem = b & 255;
    const int ti = rem >> 4;
    const int tj = rem & 15;
    const void* Ws[6] = {wxi, whi, wxc, whc, wxo, who};
    const void* W = Ws[mat];
    const int gt = mat >> 1;
    const int half = mat & 1;
    const int rrow = tid >> 3;
    const int c8 = (tid & 7) * 8;
#pragma unroll
    for (int it = 0; it < 2; ++it) {
      int row = it * 32 + rrow;
      size_t off = (size_t)(ti * 64 + row) * 1024 + tj * 64 + c8;
      if (isbf) {
        const unsigned short* s = (const unsigned short*)W + off;
        ushort4 a = *(const ushort4*)(s);
        ushort4 bv = *(const ushort4*)(s + 4);
        tbuf[row][c8+0]=b2f(a.x);  tbuf[row][c8+1]=b2f(a.y);
        tbuf[row][c8+2]=b2f(a.z);  tbuf[row][c8+3]=b2f(a.w);
        tbuf[row][c8+4]=b2f(bv.x); tbuf[row][c8+5]=b2f(bv.y);
        tbuf[row][c8+6]=b2f(bv.z); tbuf[row][c8+7]=b2f(bv.w);
      } else {
        const float* s = (const float*)W + off;
        float4 a = *(const float4*)(s);
        float4 bv = *(const float4*)(s + 4);
        tbuf[row][c8+0]=a.x;  tbuf[row][c8+1]=a.y;  tbuf[row][c8+2]=a.z;  tbuf[row][c8+3]=a.w;
        tbuf[row][c8+4]=bv.x; tbuf[row][c8+5]=bv.y; tbuf[row][c8+6]=bv.z; tbuf[row][c8+7]=bv.w;
      }
    }
    __syncthreads();
#pragma unroll
    for (int it = 0; it < 2; ++it) {
      int nl = it * 32 + rrow;
      int n = gt * 1024 + tj * 64 + nl;
      int kk = half * 1024 + ti * 64 + c8;
      short8 pk;
#pragma unroll
      for (int i = 0; i < 8; ++i) pk[i] = (short)f2b(tbuf[c8 + i][nl]);
      *(short8*)(WT + (size_t)n * KDIM + kk) = pk;
    }
  } else {
    // ---------------- f32 fallback A-pack
    if (isbf) return;
    size_t idx = ((size_t)(bx - 2048) * 256 + tid) * 8;
    int k = (int)(idx & 2047);
    size_t m = idx >> 11;
    const float* s = (k < 1024) ? (const float*)x + m * 1024 + k
                                : (const float*)h + m * 1024 + (k - 1024);
    float4 a = *(const float4*)(s);
    float4 b = *(const float4*)(s + 4);
    short8 pk;
    pk[0]=(short)f2b(a.x); pk[1]=(short)f2b(a.y); pk[2]=(short)f2b(a.z); pk[3]=(short)f2b(a.w);
    pk[4]=(short)f2b(b.x); pk[5]=(short)f2b(b.y); pk[6]=(short)f2b(b.z); pk[7]=(short)f2b(b.w);
    *(short8*)(A + idx) = pk;
  }
}

// =============================================================== k_gemm (R2)
__global__ __launch_bounds__(256, 3) void k_gemm(
    const void* __restrict__ x, const void* __restrict__ h,
    const unsigned short* __restrict__ Apack,
    const unsigned short* __restrict__ WT,
    unsigned short* __restrict__ P) {
  const int isbf = detect_bf(x);
  const unsigned short* Ax = isbf ? (const unsigned short*)x : Apack;
  const unsigned short* Ah = isbf ? (const unsigned short*)h : (Apack + 1024);
  const int sA = isbf ? 1024 : 2048;
  __shared__ __align__(16) unsigned short lA[128 * 64];
  __shared__ __align__(16) unsigned short lB[128 * 64];
  const int tid = threadIdx.x;
  const int lane = tid & 63;
  const int wv = tid >> 6;
  const int wm = (wv >> 1) << 6;
  const int wn = (wv & 1) << 6;
  const int m0 = blockIdx.y << 7;
  const int n0 = blockIdx.x << 7;

  floatx4 acc[4][4];
  const floatx4 fzero = {0.f, 0.f, 0.f, 0.f};
#pragma unroll
  for (int i = 0; i < 4; ++i)
#pragma unroll
    for (int j = 0; j < 4; ++j) acc[i][j] = fzero;

  int rr[4], kk[4];
#pragma unroll
  for (int ps = 0; ps < 4; ++ps) {
    int chunk = ps * 256 + tid;
    rr[ps] = chunk >> 3;
    kk[ps] = (chunk & 7) ^ (rr[ps] & 7);
  }
  const int px0 = (lane >> 4) ^ (lane & 7);
  const int px1 = ((lane >> 4) + 4) ^ (lane & 7);
  const int rowA = wm + (lane & 15);
  const int rowB = wn + (lane & 15);

  for (int kt = 0; kt < KDIM / 64; ++kt) {
    const int k0 = kt * 64;
    const unsigned short* Abase = (k0 < 1024) ? (Ax + k0) : (Ah + (k0 - 1024));
#pragma unroll
    for (int ps = 0; ps < 4; ++ps) {
      const int chunk = ps * 256 + tid;
      gld16(Abase + (size_t)(m0 + rr[ps]) * sA + kk[ps] * 8, lA + chunk * 8);
      gld16(WT + ((size_t)(n0 + rr[ps]) * KDIM + k0 + kk[ps] * 8), lB + chunk * 8);
    }
    __syncthreads();
#pragma unroll
    for (int s = 0; s < 2; ++s) {
      const int px = s ? px1 : px0;
      short8 af[4], bfr[4];
#pragma unroll
      for (int i = 0; i < 4; ++i)
        af[i] = *(const short8*)(lA + ((((rowA + (i << 4)) << 3) + px) << 3));
#pragma unroll
      for (int i = 0; i < 4; ++i)
        bfr[i] = *(const short8*)(lB + ((((rowB + (i << 4)) << 3) + px) << 3));
#pragma unroll
      for (int mi = 0; mi < 4; ++mi)
#pragma unroll
        for (int ni = 0; ni < 4; ++ni)
          acc[mi][ni] = __builtin_amdgcn_mfma_f32_16x16x32_bf16(
              af[mi], bfr[ni], acc[mi][ni], 0, 0, 0);
    }
    __syncthreads();
  }
  const int col = lane & 15;
  const int rq = (lane >> 4) << 2;
#pragma unroll
  for (int mi = 0; mi < 4; ++mi) {
#pragma unroll
    for (int ni = 0; ni < 4; ++ni) {
      const size_t n = (size_t)(n0 + wn + (ni << 4) + col);
#pragma unroll
      for (int t = 0; t < 4; ++t) {
        const size_t m = (size_t)(m0 + wm + (mi << 4) + rq + t);
        P[m * NDIM + n] = f2b(acc[mi][ni][t]);
      }
    }
  }
}

// =============================================================== k_pointwise
__global__ __launch_bounds__(256) void k_pointwise(
    const unsigned short* __restrict__ P, const void* __restrict__ x,
    const void* __restrict__ cin,
    const void* __restrict__ bi, const void* __restrict__ bc,
    const void* __restrict__ bo, const float* __restrict__ z2,
    const void* __restrict__ W3, const void* __restrict__ b3,
    void* __restrict__ out) {
  const int isbf = detect_bf(x);
  __shared__ unsigned short w3s[8192];  // [8][1024]
  const int tid = threadIdx.x;
#pragma unroll
  for (int it = 0; it < 4; ++it) {
    const int idx = (it * 256 + tid) * 8;
    if (isbf) {
      *(short8*)(w3s + idx) = *(const short8*)((const unsigned short*)W3 + idx);
    } else {
      const float* s = (const float*)W3 + idx;
      float4 a = *(const float4*)(s);
      float4 b = *(const float4*)(s + 4);
      short8 pk;
      pk[0]=(short)f2b(a.x); pk[1]=(short)f2b(a.y); pk[2]=(short)f2b(a.z); pk[3]=(short)f2b(a.w);
      pk[4]=(short)f2b(b.x); pk[5]=(short)f2b(b.y); pk[6]=(short)f2b(b.z); pk[7]=(short)f2b(b.w);
      *(short8*)(w3s + idx) = pk;
    }
  }
  __syncthreads();
  const size_t MH = (size_t)BATCH * HDIM;
  const size_t m = blockIdx.x;
  const int n = tid * 4;
  const size_t idx = m * 1024 + n;
  const unsigned short* pr = P + m * NDIM + n;
  ushort4 ui = *(const ushort4*)(pr);
  ushort4 ug = *(const ushort4*)(pr + 1024);
  ushort4 uo = *(const ushort4*)(pr + 2048);
  float pi[4] = {b2f(ui.x), b2f(ui.y), b2f(ui.z), b2f(ui.w)};
  float pg[4] = {b2f(ug.x), b2f(ug.y), b2f(ug.z), b2f(ug.w)};
  float po[4] = {b2f(uo.x), b2f(uo.y), b2f(uo.z), b2f(uo.w)};
  float4 za = *(const float4*)(z2 + m * 8);
  float4 zb = *(const float4*)(z2 + m * 8 + 4);
  float zz[8] = {za.x, za.y, za.z, za.w, zb.x, zb.y, zb.z, zb.w};
  float f3[4];
  float bif[4], bcf[4], bof[4], cf[4];
  if (isbf) {
    ushort4 u3 = *(const ushort4*)((const unsigned short*)b3 + n);
    f3[0]=b2f(u3.x); f3[1]=b2f(u3.y); f3[2]=b2f(u3.z); f3[3]=b2f(u3.w);
    ushort4 a = *(const ushort4*)((const unsigned short*)bi + n);
    ushort4 b = *(const ushort4*)((const unsigned short*)bc + n);
    ushort4 d = *(const ushort4*)((const unsigned short*)bo + n);
    ushort4 e = *(const ushort4*)((const unsigned short*)cin + idx);
    bif[0]=b2f(a.x); bif[1]=b2f(a.y); bif[2]=b2f(a.z); bif[3]=b2f(a.w);
    bcf[0]=b2f(b.x); bcf[1]=b2f(b.y); bcf[2]=b2f(b.z); bcf[3]=b2f(b.w);
    bof[0]=b2f(d.x); bof[1]=b2f(d.y); bof[2]=b2f(d.z); bof[3]=b2f(d.w);
    cf[0]=b2f(e.x);  cf[1]=b2f(e.y);  cf[2]=b2f(e.z);  cf[3]=b2f(e.w);
  } else {
    float4 u3 = *(const float4*)((const float*)b3 + n);
    f3[0]=u3.x; f3[1]=u3.y; f3[2]=u3.z; f3[3]=u3.w;
    float4 a = *(const float4*)((const float*)bi + n);
    float4 b = *(const float4*)((const float*)bc + n);
    float4 d = *(const float4*)((const float*)bo + n);
    float4 e = *(const float4*)((const float*)cin + idx);
    bif[0]=a.x; bif[1]=a.y; bif[2]=a.z; bif[3]=a.w;
    bcf[0]=b.x; bcf[1]=b.y; bcf[2]=b.z; bcf[3]=b.w;
    bof[0]=d.x; bof[1]=d.y; bof[2]=d.z; bof[3]=d.w;
    cf[0]=e.x;  cf[1]=e.y;  cf[2]=e.z;  cf[3]=e.w;
  }
#pragma unroll
  for (int j = 0; j < 8; ++j) {
    const unsigned short* wr = w3s + j * 1024 + n;
    f3[0] += zz[j] * b2f(wr[0]);
    f3[1] += zz[j] * b2f(wr[1]);
    f3[2] += zz[j] * b2f(wr[2]);
    f3[3] += zz[j] * b2f(wr[3]);
  }
  float hn[4], cn[4], ff[4];
#pragma unroll
  for (int t = 0; t < 4; ++t) {
    float F = sigf(f3[t]);
    float I = sigf(pi[t] + bif[t]);
    float G = tanhfast(pg[t] + bcf[t]);
    float O = sigf(po[t] + bof[t]);
    float C = F * cf[t] + I * G;
    ff[t] = F;
    cn[t] = C;
    hn[t] = O * tanhfast(C);
  }
  if (isbf) {
    unsigned short* ob = (unsigned short*)out;
    *(ushort4*)(ob + idx) = make_ushort4(f2b(hn[0]), f2b(hn[1]), f2b(hn[2]), f2b(hn[3]));
    *(ushort4*)(ob + MH + idx) = make_ushort4(f2b(cn[0]), f2b(cn[1]), f2b(cn[2]), f2b(cn[3]));
    *(ushort4*)(ob + 2 * MH + idx) = make_ushort4(f2b(ff[0]), f2b(ff[1]), f2b(ff[2]), f2b(ff[3]));
  } else {
    float* ob = (float*)out;
    *(float4*)(ob + idx) = make_float4(hn[0], hn[1], hn[2], hn[3]);
    *(float4*)(ob + MH + idx) = make_float4(cn[0], cn[1], cn[2], cn[3]);
    *(float4*)(ob + 2 * MH + idx) = make_float4(ff[0], ff[1], ff[2], ff[3]);
  }
}

extern "C" void kernel_launch(void* const* d_in, const int* in_sizes, int n_in,
                              void* d_out, int out_size, void* d_ws, size_t ws_size,
                              hipStream_t stream) {
  const void* x    = d_in[0];
  const void* h    = d_in[1];
  const void* c    = d_in[2];
  const void* W_hi = d_in[3];
  const void* W_xi = d_in[4];
  const void* b_i  = d_in[5];
  const void* W_hc = d_in[6];
  const void* W_xc = d_in[7];
  const void* b_c  = d_in[8];
  const void* W_ho = d_in[9];
  const void* W_xo = d_in[10];
  const void* b_o  = d_in[11];
  const void* W1   = d_in[12];
  const void* b1   = d_in[13];
  const void* W2   = d_in[14];
  const void* b2   = d_in[15];
  const void* W3   = d_in[16];
  const void* b3   = d_in[17];

  char* ws = (char*)d_ws;
  unsigned short* A   = (unsigned short*)ws;                 // 33.5 MB (f32 path)
  unsigned short* WT  = (unsigned short*)(ws + 33554432);    // 12.6 MB
  unsigned short* P   = (unsigned short*)(ws + 46137344);    // 50.3 MB
  float*          z2b = (float*)(ws + 96468992);             // 256 KB

  k_all<<<dim3(512 + 1536 + 8192), dim3(256), 0, stream>>>(
      x, h, W_xi, W_hi, W_xc, W_hc, W_xo, W_ho, W1, b_i ? b1 : b1, W2, b2,
      WT, A, z2b);
  k_gemm<<<dim3(NDIM / 128, BATCH / 128), dim3(256), 0, stream>>>(x, h, A, WT, P);
  k_pointwise<<<dim3(BATCH), dim3(256), 0, stream>>>(P, x, c, b_i, b_c, b_o,
                                                     z2b, W3, b3, d_out);
}